// Round 20
// baseline (361.893 us; speedup 1.0000x reference)
//
#include <hip/hip_runtime.h>
#include <hip/hip_bf16.h>
#include <math.h>
#include <float.h>

#define B_    32
#define C_    1536
#define T_    2000
#define TP_   2048  // padded T for xt
#define BOT_  128
#define EPS_  1e-4f

#define CH    64    // c-chunk, phase 1
#define NCH   24    // C_/CH
#define TC    128   // t-chunk per block (fused)
#define NTS   16    // 2048/128
#define NT_ST 8     // t-chunks for stats kernel (2048/256)

typedef __attribute__((ext_vector_type(8))) short short8;
typedef __attribute__((ext_vector_type(4))) short short4v;
typedef __attribute__((ext_vector_type(4))) float f32x4;

static __device__ __forceinline__ unsigned short f2bf(float f) {
    unsigned u = __float_as_uint(f);
    u += 0x7FFFu + ((u >> 16) & 1u);           // RTNE
    return (unsigned short)(u >> 16);
}
static __device__ __forceinline__ float bf2f(unsigned short u) {
    return __uint_as_float(((unsigned)u) << 16);
}

// ---------------------------------------------------------------------------
// K1: bf16 transpose xt[b][t][c] (t zero-padded to 2048) + per-(b,c) partial
// sums s1/s2 over a 256-t chunk. Grid (C/64, NT_ST+1, B); the extra y-plane
// (tc == NT_ST) converts W1[:, :C] and W2 to bf16 (no LDS/barrier path).
// ---------------------------------------------------------------------------
__global__ __launch_bounds__(256) void stats_transpose(
    const float* __restrict__ x, float* __restrict__ spart,
    unsigned short* __restrict__ xt,
    const float* __restrict__ W1, const float* __restrict__ W2,
    unsigned short* __restrict__ W1b, unsigned short* __restrict__ W2b) {
    const int tc  = blockIdx.y;
    const int b   = blockIdx.z;
    const int tid = threadIdx.x;

    if (tc == NT_ST) {   // cvt plane: 768 blocks x 256 thr = 196608 elements
        int base = (b * (C_ / 64) + blockIdx.x) * 256 + tid;  // 0..196607
        int o = base / C_, c = base - o * C_;
        W1b[base] = f2bf(W1[(size_t)o * (3 * C_) + c]);
        W2b[base] = f2bf(W2[base]);
        return;
    }

    const int cb0 = blockIdx.x * 64;
    const int crow = tid >> 4;       // 0..15 (base read row)
    const int t4   = tid & 15;       // float4 index along t

    __shared__ __align__(16) unsigned short Tl[64 * 72];   // [t][c], stride 72

    const float* xb = x + ((size_t)b * C_ + cb0) * T_;
    unsigned short* xo = xt + (size_t)b * TP_ * C_ + cb0;

    float s1[4] = {0.f, 0.f, 0.f, 0.f}, s2[4] = {0.f, 0.f, 0.f, 0.f};

    const int tt0 = tc * 256;
    for (int tt = tt0; tt < tt0 + 256; tt += 64) {
        __syncthreads();   // prior tile's Tl reads complete
        const int tg = tt + t4 * 4;
        #pragma unroll
        for (int i = 0; i < 4; ++i) {
            const int c = crow + 16 * i;
            f32x4 v;
            if (tg < T_) {          // T%4==0 -> float4 fully valid
                v = *reinterpret_cast<const f32x4*>(xb + (size_t)c * T_ + tg);
            } else {
                v = (f32x4){0.f, 0.f, 0.f, 0.f};
            }
            s1[i] += (v[0] + v[1]) + (v[2] + v[3]);
            s2[i] = fmaf(v[0], v[0], fmaf(v[1], v[1],
                    fmaf(v[2], v[2], fmaf(v[3], v[3], s2[i]))));
            #pragma unroll
            for (int j = 0; j < 4; ++j)
                Tl[(t4 * 4 + j) * 72 + c] = f2bf(v[j]);
        }
        __syncthreads();
        #pragma unroll
        for (int jj = 0; jj < 2; ++jj) {
            int idx = tid + 256 * jj;            // 0..511
            int t = idx >> 3, c8 = idx & 7;
            short8 vv = *reinterpret_cast<const short8*>(&Tl[t * 72 + c8 * 8]);
            *reinterpret_cast<short8*>(xo + (size_t)(tt + t) * C_ + c8 * 8) = vv;
        }
    }

    #pragma unroll
    for (int i = 0; i < 4; ++i) {
        #pragma unroll
        for (int off = 1; off < 16; off <<= 1) {
            s1[i] += __shfl_xor(s1[i], off);
            s2[i] += __shfl_xor(s2[i], off);
        }
    }
    if (t4 == 0) {
        float* sp = spart + ((size_t)(b * NT_ST + tc) * 2) * C_ + cb0;
        #pragma unroll
        for (int i = 0; i < 4; ++i) {
            const int c = crow + 16 * i;
            sp[c]      = s1[i];
            sp[C_ + c] = s2[i];
        }
    }
}

// ---------------------------------------------------------------------------
// K2 (fused, counted-vmcnt pipeline, 8 waves + setprio, inline cb):
//  prologue: fold spart -> mean/std (ring-LDS scratch), compute this
//    block's cb[128] into a 512B LDS slot ABOVE the rings (fp32, exact).
//    All vector loads retire before the first glds -> vmcnt clean.
//  phase 1: W1-tile + X-tile staged via global_load_lds (4 glds/thread/
//    chunk), double-buffered; raw s_barrier + counted vmcnt(4).
//    Wave = (o-half x t-quarter); MFMA wrapped in setprio(1).
//  epilogue: +cb(LDS), relu -> Hl[128t][128o] bf16 (union over buffer 0).
//  phase 2: swapped MFMA (A = Hl t-rows, B = W2 c-rows), lane=c, regs=t;
//    max-free exp (|L|<~3, b2 cancels); x from xt; 2-shfl reduce.
// LDS = 64.5 KB -> 2 blocks/CU, 16 waves/CU.
// ---------------------------------------------------------------------------
typedef const __attribute__((address_space(1))) unsigned int* gas_ptr;
typedef __attribute__((address_space(3))) unsigned int* las_ptr;

__global__ __launch_bounds__(512) void fused_main(
    const unsigned short* __restrict__ xt,
    const unsigned short* __restrict__ W1b, const unsigned short* __restrict__ W2b,
    const float* __restrict__ W1, const float* __restrict__ b1,
    const float* __restrict__ spart, float* __restrict__ part) {
    const int b   = blockIdx.y;
    const int ts  = blockIdx.x;
    const int t0  = ts * TC;
    const int tid = threadIdx.x;
    const int lane = tid & 63;
    const int w   = tid >> 6;            // 0..7
    const int oh  = w >> 2, th = w & 3;  // o-half (64), t-quarter (32)
    const int g   = lane >> 4, li = lane & 15;

    // LDS: rings buf p at p*16384 ushorts: [X 8192][W 8192] (64KB);
    // cbl (128 floats) above at ushort offset 32768. Hl = first 16384.
    __shared__ __align__(16) unsigned short LDS[4 * 8192 + 256];
    unsigned short* Hl = LDS;
    float* cbl = reinterpret_cast<float*>(LDS + 4 * 8192);

    const unsigned short* xtb = xt + (size_t)b * TP_ * C_;

    // ---------------- prologue: inline cb ----------------
    {
        float* mlp = reinterpret_cast<float*>(LDS);        // 1536 f
        float* slp = mlp + C_;                             // 1536 f
        for (int c = tid; c < C_; c += 512) {
            float s1 = 0.f, s2 = 0.f;
            #pragma unroll
            for (int tc = 0; tc < NT_ST; ++tc) {
                const float* sp = spart + ((size_t)(b * NT_ST + tc) * 2) * C_ + c;
                s1 += sp[0];
                s2 += sp[C_];
            }
            float mean = s1 / (float)T_;
            float var  = (s2 - s1 * mean) / (float)(T_ - 1);
            mlp[c] = mean;
            slp[c] = sqrtf(fmaxf(var, EPS_));
        }
        __syncthreads();
        const int o = tid >> 2, q = tid & 3;   // 4 threads per o-row
        const float* wm = W1 + (size_t)o * (3 * C_) + C_;
        const float* ws = wm + C_;
        float am = 0.f, as = 0.f;
        const int c0 = q * 384;
        #pragma unroll 4
        for (int k = 0; k < 96; ++k) {
            const int c = c0 + k * 4;
            float4 wmv = *reinterpret_cast<const float4*>(wm + c);
            float4 wsv = *reinterpret_cast<const float4*>(ws + c);
            float4 mlv = *reinterpret_cast<const float4*>(&mlp[c]);
            float4 slv = *reinterpret_cast<const float4*>(&slp[c]);
            am = fmaf(wmv.x, mlv.x, fmaf(wmv.y, mlv.y,
                 fmaf(wmv.z, mlv.z, fmaf(wmv.w, mlv.w, am))));
            as = fmaf(wsv.x, slv.x, fmaf(wsv.y, slv.y,
                 fmaf(wsv.z, slv.z, fmaf(wsv.w, slv.w, as))));
        }
        float v = am + as;
        v += __shfl_xor(v, 1); v += __shfl_xor(v, 2);
        if (q == 0) cbl[o] = b1[o] + v;
        __syncthreads();   // mlp/slp reads done; cbl ready; rings may now be written
    }

    // ---------------- phase 1 ----------------
    f32x4 hacc[4][2];
    #pragma unroll
    for (int mi = 0; mi < 4; ++mi)
        #pragma unroll
        for (int ni = 0; ni < 2; ++ni)
            hacc[mi][ni] = (f32x4){0.f, 0.f, 0.f, 0.f};

    // glds sources: slot s = i*512+tid -> row r = s>>3, sl = s&7;
    // source column block pre-swizzled (inverse of read swizzle).
    const unsigned short* gX[2];
    const unsigned short* gW[2];
    #pragma unroll
    for (int i = 0; i < 2; ++i) {
        int s = i * 512 + tid;
        int r = s >> 3, sl = s & 7;
        gX[i] = xtb + (size_t)(t0 + r) * C_ + ((sl ^ (r & 7)) * 8);
        gW[i] = W1b + (size_t)r * C_ + ((sl ^ (r & 7)) * 8);
    }

    auto STAGE = [&](int p, int kc) {
        unsigned short* bx = LDS + p * 16384;
        unsigned short* bw = bx + 8192;
        #pragma unroll
        for (int i = 0; i < 2; ++i)
            __builtin_amdgcn_global_load_lds(
                (gas_ptr)(gX[i] + kc), (las_ptr)&bx[(i * 512 + w * 64) * 8], 16, 0, 0);
        #pragma unroll
        for (int i = 0; i < 2; ++i)
            __builtin_amdgcn_global_load_lds(
                (gas_ptr)(gW[i] + kc), (las_ptr)&bw[(i * 512 + w * 64) * 8], 16, 0, 0);
    };

    auto COMPUTE = [&](int p) {
        const unsigned short* bx = LDS + p * 16384;
        const unsigned short* bw = bx + 8192;
        __builtin_amdgcn_s_setprio(1);
        #pragma unroll
        for (int ks = 0; ks < 2; ++ks) {
            short8 a[4], bb4[2];
            #pragma unroll
            for (int mi = 0; mi < 4; ++mi) {
                int o = oh * 64 + mi * 16 + li;
                a[mi] = *reinterpret_cast<const short8*>(
                    &bw[o * 64 + (((ks * 4 + g) ^ (o & 7)) << 3)]);
            }
            #pragma unroll
            for (int ni = 0; ni < 2; ++ni) {
                int t = th * 32 + ni * 16 + li;
                bb4[ni] = *reinterpret_cast<const short8*>(
                    &bx[t * 64 + (((ks * 4 + g) ^ (t & 7)) << 3)]);
            }
            #pragma unroll
            for (int mi = 0; mi < 4; ++mi)
                #pragma unroll
                for (int ni = 0; ni < 2; ++ni)
                    hacc[mi][ni] = __builtin_amdgcn_mfma_f32_16x16x32_bf16(a[mi], bb4[ni], hacc[mi][ni], 0, 0, 0);
        }
        __builtin_amdgcn_s_setprio(0);
    };

    STAGE(0, 0);
    STAGE(1, CH);

    for (int k = 0; k < NCH - 1; ++k) {
        const int cur = k & 1;
        asm volatile("s_waitcnt vmcnt(4)" ::: "memory");   // chunk k ready
        __builtin_amdgcn_s_barrier();
        COMPUTE(cur);
        __builtin_amdgcn_s_barrier();                      // all waves done reading
        if (k + 2 < NCH) STAGE(cur, (k + 2) * CH);
    }
    asm volatile("s_waitcnt vmcnt(0)" ::: "memory");
    __builtin_amdgcn_s_barrier();
    COMPUTE((NCH - 1) & 1);

    // epilogue: +cb(LDS), relu, bf16 -> Hl[t][o] (swizzled 8B writes; union!)
    __syncthreads();
    #pragma unroll
    for (int mi = 0; mi < 4; ++mi) {
        const int ob = oh * 64 + mi * 16 + g * 4;
        const float4 cbv = *reinterpret_cast<const float4*>(&cbl[ob]);
        const int so = ob >> 3, off = ob & 7;   // off = 0 or 4
        #pragma unroll
        for (int ni = 0; ni < 2; ++ni) {
            int t = th * 32 + ni * 16 + li;
            short4v pk;
            pk[0] = (short)f2bf(fmaxf(hacc[mi][ni][0] + cbv.x, 0.f));
            pk[1] = (short)f2bf(fmaxf(hacc[mi][ni][1] + cbv.y, 0.f));
            pk[2] = (short)f2bf(fmaxf(hacc[mi][ni][2] + cbv.z, 0.f));
            pk[3] = (short)f2bf(fmaxf(hacc[mi][ni][3] + cbv.w, 0.f));
            *reinterpret_cast<short4v*>(
                &Hl[t * 128 + ((so ^ (t & 7)) << 3) + off]) = pk;
        }
    }
    __syncthreads();

    // ---------------- phase 2: swapped MFMA, lane = c ----------------
    float* pbase = part + ((size_t)(b * NTS + ts) * 3) * C_;

    for (int ccb = 0; ccb < C_; ccb += 128) {
        const int c = ccb + w * 16 + li;     // 128 c per iter across 8 waves
        short8 bfr[4];
        #pragma unroll
        for (int ks = 0; ks < 4; ++ks)
            bfr[ks] = *reinterpret_cast<const short8*>(
                W2b + (size_t)c * BOT_ + ks * 32 + g * 8);

        float Z = 0.f, S1 = 0.f, S2 = 0.f;
        #pragma unroll
        for (int th2 = 0; th2 < 2; ++th2) {
            f32x4 lacc[4];
            #pragma unroll
            for (int ni = 0; ni < 4; ++ni) lacc[ni] = (f32x4){0.f, 0.f, 0.f, 0.f};
            __builtin_amdgcn_s_setprio(1);
            #pragma unroll
            for (int ks = 0; ks < 4; ++ks) {
                short8 af[4];
                #pragma unroll
                for (int ni = 0; ni < 4; ++ni) {
                    int t = th2 * 64 + ni * 16 + li;
                    af[ni] = *reinterpret_cast<const short8*>(
                        &Hl[t * 128 + (((ks * 4 + g) ^ (t & 7)) << 3)]);
                }
                #pragma unroll
                for (int ni = 0; ni < 4; ++ni)
                    lacc[ni] = __builtin_amdgcn_mfma_f32_16x16x32_bf16(af[ni], bfr[ks], lacc[ni], 0, 0, 0);
            }
            __builtin_amdgcn_s_setprio(0);
            #pragma unroll
            for (int ni = 0; ni < 4; ++ni)
                #pragma unroll
                for (int r = 0; r < 4; ++r) {
                    int tl = th2 * 64 + ni * 16 + g * 4 + r;
                    int t  = t0 + tl;
                    float p = __expf(lacc[ni][r]);
                    p = (t < T_) ? p : 0.f;
                    float xx = bf2f(xtb[(size_t)t * C_ + c]);
                    Z += p;
                    S1 = fmaf(xx, p, S1);
                    S2 = fmaf(xx * xx, p, S2);
                }
        }
        Z  += __shfl_xor(Z, 16);  Z  += __shfl_xor(Z, 32);
        S1 += __shfl_xor(S1, 16); S1 += __shfl_xor(S1, 32);
        S2 += __shfl_xor(S2, 16); S2 += __shfl_xor(S2, 32);
        if (lane < 16) {
            pbase[c]          = Z;
            pbase[C_ + c]     = S1;
            pbase[2 * C_ + c] = S2;
        }
    }
}

// ---------------------------------------------------------------------------
// K3: fold the NTS t-chunk partials, finalize wmean/wsd.
// ---------------------------------------------------------------------------
__global__ __launch_bounds__(256) void reduce_kernel(
    const float* __restrict__ part, float* __restrict__ out) {
    const int c = blockIdx.x * 256 + threadIdx.x;
    const int b = blockIdx.y;
    float Z = 0.f, S1 = 0.f, S2 = 0.f;
    for (int ts = 0; ts < NTS; ++ts) {
        const float* pb = part + ((size_t)(b * NTS + ts) * 3) * C_ + c;
        Z  += pb[0];
        S1 += pb[C_];
        S2 += pb[2 * C_];
    }
    float wmean = S1 / Z;
    float wsd   = sqrtf(fmaxf(S2 / Z - wmean * wmean, EPS_));
    out[(size_t)b * (2 * C_) + c]      = wmean;
    out[(size_t)b * (2 * C_) + C_ + c] = wsd;
}

// ---------------------------------------------------------------------------
extern "C" void kernel_launch(void* const* d_in, const int* in_sizes, int n_in,
                              void* d_out, int out_size, void* d_ws, size_t ws_size,
                              hipStream_t stream) {
    const float* x  = (const float*)d_in[0];   // [B, C, T]
    const float* W1 = (const float*)d_in[1];   // [BOT, 3C]
    const float* b1 = (const float*)d_in[2];   // [BOT]
    const float* W2 = (const float*)d_in[3];   // [C, BOT]
    // b2 (d_in[4]) cancels in softmax over T
    float* out = (float*)d_out;                // [B, 2C]

    float* ws = (float*)d_ws;
    float* spart  = ws;                                    // B*NT_ST*2*C (3.1MB)
    float* part   = spart + (size_t)B_ * NT_ST * 2 * C_;   // B*NTS*3*C (9.4MB)
    unsigned short* W1b = (unsigned short*)(part + (size_t)B_ * NTS * 3 * C_);
    unsigned short* W2b = W1b + (size_t)BOT_ * C_;         // C*BOT
    unsigned short* xt  = W2b + (size_t)C_ * BOT_;         // B*TP*C bf16 (192MB)

    stats_transpose<<<dim3(C_ / 64, NT_ST + 1, B_), 256, 0, stream>>>(
        x, spart, xt, W1, W2, W1b, W2b);
    fused_main<<<dim3(NTS, B_), 512, 0, stream>>>(
        xt, W1b, W2b, W1, b1, spart, part);
    reduce_kernel<<<dim3(C_ / 256, B_), 256, 0, stream>>>(part, out);
}

// Round 21
// 269.755 us; speedup vs baseline: 1.3416x; 1.3416x over previous
//
#include <hip/hip_runtime.h>
#include <hip/hip_bf16.h>
#include <math.h>
#include <float.h>

#define B_    32
#define C_    1536
#define T_    2000
#define TP_   2048  // padded T for xt
#define BOT_  128
#define EPS_  1e-4f

#define CH    64    // c-chunk, phase 1
#define NCH   24    // C_/CH
#define TC    128   // t-chunk per block (fused)
#define NTS   16    // 2048/128
#define NT_ST 8     // t-chunks for stats kernel (2048/256)

typedef __attribute__((ext_vector_type(8))) short short8;
typedef __attribute__((ext_vector_type(4))) short short4v;
typedef __attribute__((ext_vector_type(4))) float f32x4;

static __device__ __forceinline__ unsigned short f2bf(float f) {
    unsigned u = __float_as_uint(f);
    u += 0x7FFFu + ((u >> 16) & 1u);           // RTNE
    return (unsigned short)(u >> 16);
}
static __device__ __forceinline__ float bf2f(unsigned short u) {
    return __uint_as_float(((unsigned)u) << 16);
}

// ---------------------------------------------------------------------------
// K1: bf16 transpose xt[b][t][c] (t zero-padded to 2048) + per-(b,c) partial
// sums s1/s2 over a 256-t chunk. Grid (C/64, NT_ST+1, B); the extra y-plane
// (tc == NT_ST) converts W1[:, :C] and W2 to bf16 (no LDS/barrier path).
// ---------------------------------------------------------------------------
__global__ __launch_bounds__(256) void stats_transpose(
    const float* __restrict__ x, float* __restrict__ spart,
    unsigned short* __restrict__ xt,
    const float* __restrict__ W1, const float* __restrict__ W2,
    unsigned short* __restrict__ W1b, unsigned short* __restrict__ W2b) {
    const int tc  = blockIdx.y;
    const int b   = blockIdx.z;
    const int tid = threadIdx.x;

    if (tc == NT_ST) {   // cvt plane: 768 blocks x 256 thr = 196608 elements
        int base = (b * (C_ / 64) + blockIdx.x) * 256 + tid;  // 0..196607
        int o = base / C_, c = base - o * C_;
        W1b[base] = f2bf(W1[(size_t)o * (3 * C_) + c]);
        W2b[base] = f2bf(W2[base]);
        return;
    }

    const int cb0 = blockIdx.x * 64;
    const int crow = tid >> 4;       // 0..15 (base read row)
    const int t4   = tid & 15;       // float4 index along t

    __shared__ __align__(16) unsigned short Tl[64 * 72];   // [t][c], stride 72

    const float* xb = x + ((size_t)b * C_ + cb0) * T_;
    unsigned short* xo = xt + (size_t)b * TP_ * C_ + cb0;

    float s1[4] = {0.f, 0.f, 0.f, 0.f}, s2[4] = {0.f, 0.f, 0.f, 0.f};

    const int tt0 = tc * 256;
    for (int tt = tt0; tt < tt0 + 256; tt += 64) {
        __syncthreads();   // prior tile's Tl reads complete
        const int tg = tt + t4 * 4;
        #pragma unroll
        for (int i = 0; i < 4; ++i) {
            const int c = crow + 16 * i;
            f32x4 v;
            if (tg < T_) {          // T%4==0 -> float4 fully valid
                v = *reinterpret_cast<const f32x4*>(xb + (size_t)c * T_ + tg);
            } else {
                v = (f32x4){0.f, 0.f, 0.f, 0.f};
            }
            s1[i] += (v[0] + v[1]) + (v[2] + v[3]);
            s2[i] = fmaf(v[0], v[0], fmaf(v[1], v[1],
                    fmaf(v[2], v[2], fmaf(v[3], v[3], s2[i]))));
            #pragma unroll
            for (int j = 0; j < 4; ++j)
                Tl[(t4 * 4 + j) * 72 + c] = f2bf(v[j]);
        }
        __syncthreads();
        #pragma unroll
        for (int jj = 0; jj < 2; ++jj) {
            int idx = tid + 256 * jj;            // 0..511
            int t = idx >> 3, c8 = idx & 7;
            short8 vv = *reinterpret_cast<const short8*>(&Tl[t * 72 + c8 * 8]);
            *reinterpret_cast<short8*>(xo + (size_t)(tt + t) * C_ + c8 * 8) = vv;
        }
    }

    #pragma unroll
    for (int i = 0; i < 4; ++i) {
        #pragma unroll
        for (int off = 1; off < 16; off <<= 1) {
            s1[i] += __shfl_xor(s1[i], off);
            s2[i] += __shfl_xor(s2[i], off);
        }
    }
    if (t4 == 0) {
        float* sp = spart + ((size_t)(b * NT_ST + tc) * 2) * C_ + cb0;
        #pragma unroll
        for (int i = 0; i < 4; ++i) {
            const int c = crow + 16 * i;
            sp[c]      = s1[i];
            sp[C_ + c] = s2[i];
        }
    }
}

// ---------------------------------------------------------------------------
// K2: fold stats partials -> mean/std (LDS), then
// cb[b][o] = b1[o] + sum_c W1[o][C+c]*mean[c] + W1[o][2C+c]*std[c].
// (r17-verified version — computed ONCE per b, coalesced 16-thread rows.)
// ---------------------------------------------------------------------------
__global__ __launch_bounds__(256) void cb_kernel(
    const float* __restrict__ W1, const float* __restrict__ b1,
    const float* __restrict__ spart, float* __restrict__ cb) {
    __shared__ __align__(16) float ml[C_];
    __shared__ __align__(16) float sl[C_];
    const int b = blockIdx.x, tid = threadIdx.x;

    for (int c = tid; c < C_; c += 256) {
        float s1 = 0.f, s2 = 0.f;
        #pragma unroll
        for (int tc = 0; tc < NT_ST; ++tc) {
            const float* sp = spart + ((size_t)(b * NT_ST + tc) * 2) * C_ + c;
            s1 += sp[0];
            s2 += sp[C_];
        }
        float mean = s1 / (float)T_;
        float var  = (s2 - s1 * mean) / (float)(T_ - 1);
        ml[c] = mean;
        sl[c] = sqrtf(fmaxf(var, EPS_));
    }
    __syncthreads();

    const int grp = tid >> 4, j = tid & 15;
    #pragma unroll
    for (int p = 0; p < 8; ++p) {
        const int o = p * 16 + grp;
        const float* wm = W1 + (size_t)o * (3 * C_) + C_;
        const float* ws = wm + C_;
        float am = 0.f, as = 0.f;
        #pragma unroll 4
        for (int k = 0; k < 24; ++k) {
            const int c = k * 64 + j * 4;
            float4 wmv = *reinterpret_cast<const float4*>(wm + c);
            float4 wsv = *reinterpret_cast<const float4*>(ws + c);
            float4 mlv = *reinterpret_cast<const float4*>(&ml[c]);
            float4 slv = *reinterpret_cast<const float4*>(&sl[c]);
            am = fmaf(wmv.x, mlv.x, fmaf(wmv.y, mlv.y,
                 fmaf(wmv.z, mlv.z, fmaf(wmv.w, mlv.w, am))));
            as = fmaf(wsv.x, slv.x, fmaf(wsv.y, slv.y,
                 fmaf(wsv.z, slv.z, fmaf(wsv.w, slv.w, as))));
        }
        float v = am + as;
        v += __shfl_xor(v, 1); v += __shfl_xor(v, 2);
        v += __shfl_xor(v, 4); v += __shfl_xor(v, 8);
        if (j == 0) cb[(size_t)b * BOT_ + o] = b1[o] + v;
    }
}

// ---------------------------------------------------------------------------
// K3 (fused, counted-vmcnt pipeline, 8 waves + setprio) — r17-verified.
// ---------------------------------------------------------------------------
typedef const __attribute__((address_space(1))) unsigned int* gas_ptr;
typedef __attribute__((address_space(3))) unsigned int* las_ptr;

__global__ __launch_bounds__(512) void fused_main(
    const unsigned short* __restrict__ xt,
    const unsigned short* __restrict__ W1b, const unsigned short* __restrict__ W2b,
    const float* __restrict__ cb, float* __restrict__ part) {
    const int b   = blockIdx.y;
    const int ts  = blockIdx.x;
    const int t0  = ts * TC;
    const int tid = threadIdx.x;
    const int lane = tid & 63;
    const int w   = tid >> 6;            // 0..7
    const int oh  = w >> 2, th = w & 3;  // o-half (64), t-quarter (32)
    const int g   = lane >> 4, li = lane & 15;

    // LDS: buf p at p*16384 ushorts: [X 8192][W 8192]. Hl = first 16384.
    __shared__ __align__(16) unsigned short LDS[4 * 8192];  // 64KB
    unsigned short* Hl = LDS;

    const unsigned short* xtb = xt + (size_t)b * TP_ * C_;

    // ---------------- phase 1 ----------------
    f32x4 hacc[4][2];
    #pragma unroll
    for (int mi = 0; mi < 4; ++mi)
        #pragma unroll
        for (int ni = 0; ni < 2; ++ni)
            hacc[mi][ni] = (f32x4){0.f, 0.f, 0.f, 0.f};

    // glds sources: slot s = i*512+tid -> row r = s>>3, sl = s&7;
    // source column block pre-swizzled (inverse of read swizzle).
    const unsigned short* gX[2];
    const unsigned short* gW[2];
    #pragma unroll
    for (int i = 0; i < 2; ++i) {
        int s = i * 512 + tid;
        int r = s >> 3, sl = s & 7;
        gX[i] = xtb + (size_t)(t0 + r) * C_ + ((sl ^ (r & 7)) * 8);
        gW[i] = W1b + (size_t)r * C_ + ((sl ^ (r & 7)) * 8);
    }

    auto STAGE = [&](int p, int kc) {
        unsigned short* bx = LDS + p * 16384;
        unsigned short* bw = bx + 8192;
        #pragma unroll
        for (int i = 0; i < 2; ++i)
            __builtin_amdgcn_global_load_lds(
                (gas_ptr)(gX[i] + kc), (las_ptr)&bx[(i * 512 + w * 64) * 8], 16, 0, 0);
        #pragma unroll
        for (int i = 0; i < 2; ++i)
            __builtin_amdgcn_global_load_lds(
                (gas_ptr)(gW[i] + kc), (las_ptr)&bw[(i * 512 + w * 64) * 8], 16, 0, 0);
    };

    auto COMPUTE = [&](int p) {
        const unsigned short* bx = LDS + p * 16384;
        const unsigned short* bw = bx + 8192;
        __builtin_amdgcn_s_setprio(1);
        #pragma unroll
        for (int ks = 0; ks < 2; ++ks) {
            short8 a[4], bb4[2];
            #pragma unroll
            for (int mi = 0; mi < 4; ++mi) {
                int o = oh * 64 + mi * 16 + li;
                a[mi] = *reinterpret_cast<const short8*>(
                    &bw[o * 64 + (((ks * 4 + g) ^ (o & 7)) << 3)]);
            }
            #pragma unroll
            for (int ni = 0; ni < 2; ++ni) {
                int t = th * 32 + ni * 16 + li;
                bb4[ni] = *reinterpret_cast<const short8*>(
                    &bx[t * 64 + (((ks * 4 + g) ^ (t & 7)) << 3)]);
            }
            #pragma unroll
            for (int mi = 0; mi < 4; ++mi)
                #pragma unroll
                for (int ni = 0; ni < 2; ++ni)
                    hacc[mi][ni] = __builtin_amdgcn_mfma_f32_16x16x32_bf16(a[mi], bb4[ni], hacc[mi][ni], 0, 0, 0);
        }
        __builtin_amdgcn_s_setprio(0);
    };

    STAGE(0, 0);
    STAGE(1, CH);

    for (int k = 0; k < NCH - 1; ++k) {
        const int cur = k & 1;
        asm volatile("s_waitcnt vmcnt(4)" ::: "memory");   // chunk k ready
        __builtin_amdgcn_s_barrier();
        COMPUTE(cur);
        __builtin_amdgcn_s_barrier();                      // all waves done reading
        if (k + 2 < NCH) STAGE(cur, (k + 2) * CH);
    }
    asm volatile("s_waitcnt vmcnt(0)" ::: "memory");
    __builtin_amdgcn_s_barrier();
    COMPUTE((NCH - 1) & 1);

    // epilogue: +cb, relu, bf16 -> Hl[t][o] (swizzled 8B writes; union!)
    __syncthreads();
    #pragma unroll
    for (int mi = 0; mi < 4; ++mi) {
        const int ob = oh * 64 + mi * 16 + g * 4;
        const float4 cbv = *reinterpret_cast<const float4*>(cb + (size_t)b * BOT_ + ob);
        const int so = ob >> 3, off = ob & 7;   // off = 0 or 4
        #pragma unroll
        for (int ni = 0; ni < 2; ++ni) {
            int t = th * 32 + ni * 16 + li;
            short4v pk;
            pk[0] = (short)f2bf(fmaxf(hacc[mi][ni][0] + cbv.x, 0.f));
            pk[1] = (short)f2bf(fmaxf(hacc[mi][ni][1] + cbv.y, 0.f));
            pk[2] = (short)f2bf(fmaxf(hacc[mi][ni][2] + cbv.z, 0.f));
            pk[3] = (short)f2bf(fmaxf(hacc[mi][ni][3] + cbv.w, 0.f));
            *reinterpret_cast<short4v*>(
                &Hl[t * 128 + ((so ^ (t & 7)) << 3) + off]) = pk;
        }
    }
    __syncthreads();

    // ---------------- phase 2: swapped MFMA, lane = c ----------------
    float* pbase = part + ((size_t)(b * NTS + ts) * 3) * C_;

    for (int ccb = 0; ccb < C_; ccb += 128) {
        const int c = ccb + w * 16 + li;     // 128 c per iter across 8 waves
        short8 bfr[4];
        #pragma unroll
        for (int ks = 0; ks < 4; ++ks)
            bfr[ks] = *reinterpret_cast<const short8*>(
                W2b + (size_t)c * BOT_ + ks * 32 + g * 8);

        float Z = 0.f, S1 = 0.f, S2 = 0.f;
        #pragma unroll
        for (int th2 = 0; th2 < 2; ++th2) {
            f32x4 lacc[4];
            #pragma unroll
            for (int ni = 0; ni < 4; ++ni) lacc[ni] = (f32x4){0.f, 0.f, 0.f, 0.f};
            __builtin_amdgcn_s_setprio(1);
            #pragma unroll
            for (int ks = 0; ks < 4; ++ks) {
                short8 af[4];
                #pragma unroll
                for (int ni = 0; ni < 4; ++ni) {
                    int t = th2 * 64 + ni * 16 + li;
                    af[ni] = *reinterpret_cast<const short8*>(
                        &Hl[t * 128 + (((ks * 4 + g) ^ (t & 7)) << 3)]);
                }
                #pragma unroll
                for (int ni = 0; ni < 4; ++ni)
                    lacc[ni] = __builtin_amdgcn_mfma_f32_16x16x32_bf16(af[ni], bfr[ks], lacc[ni], 0, 0, 0);
            }
            __builtin_amdgcn_s_setprio(0);
            #pragma unroll
            for (int ni = 0; ni < 4; ++ni)
                #pragma unroll
                for (int r = 0; r < 4; ++r) {
                    int tl = th2 * 64 + ni * 16 + g * 4 + r;
                    int t  = t0 + tl;
                    float p = __expf(lacc[ni][r]);
                    p = (t < T_) ? p : 0.f;
                    float xx = bf2f(xtb[(size_t)t * C_ + c]);
                    Z += p;
                    S1 = fmaf(xx, p, S1);
                    S2 = fmaf(xx * xx, p, S2);
                }
        }
        Z  += __shfl_xor(Z, 16);  Z  += __shfl_xor(Z, 32);
        S1 += __shfl_xor(S1, 16); S1 += __shfl_xor(S1, 32);
        S2 += __shfl_xor(S2, 16); S2 += __shfl_xor(S2, 32);
        if (lane < 16) {
            pbase[c]          = Z;
            pbase[C_ + c]     = S1;
            pbase[2 * C_ + c] = S2;
        }
    }
}

// ---------------------------------------------------------------------------
// K4: fold the NTS t-chunk partials, finalize wmean/wsd.
// ---------------------------------------------------------------------------
__global__ __launch_bounds__(256) void reduce_kernel(
    const float* __restrict__ part, float* __restrict__ out) {
    const int c = blockIdx.x * 256 + threadIdx.x;
    const int b = blockIdx.y;
    float Z = 0.f, S1 = 0.f, S2 = 0.f;
    for (int ts = 0; ts < NTS; ++ts) {
        const float* pb = part + ((size_t)(b * NTS + ts) * 3) * C_ + c;
        Z  += pb[0];
        S1 += pb[C_];
        S2 += pb[2 * C_];
    }
    float wmean = S1 / Z;
    float wsd   = sqrtf(fmaxf(S2 / Z - wmean * wmean, EPS_));
    out[(size_t)b * (2 * C_) + c]      = wmean;
    out[(size_t)b * (2 * C_) + C_ + c] = wsd;
}

// ---------------------------------------------------------------------------
extern "C" void kernel_launch(void* const* d_in, const int* in_sizes, int n_in,
                              void* d_out, int out_size, void* d_ws, size_t ws_size,
                              hipStream_t stream) {
    const float* x  = (const float*)d_in[0];   // [B, C, T]
    const float* W1 = (const float*)d_in[1];   // [BOT, 3C]
    const float* b1 = (const float*)d_in[2];   // [BOT]
    const float* W2 = (const float*)d_in[3];   // [C, BOT]
    // b2 (d_in[4]) cancels in softmax over T
    float* out = (float*)d_out;                // [B, 2C]

    float* ws = (float*)d_ws;
    float* cb     = ws;                                    // B*BOT
    float* spart  = cb + (size_t)B_ * BOT_;                // B*NT_ST*2*C (3.1MB)
    float* part   = spart + (size_t)B_ * NT_ST * 2 * C_;   // B*NTS*3*C (9.4MB)
    unsigned short* W1b = (unsigned short*)(part + (size_t)B_ * NTS * 3 * C_);
    unsigned short* W2b = W1b + (size_t)BOT_ * C_;         // C*BOT
    unsigned short* xt  = W2b + (size_t)C_ * BOT_;         // B*TP*C bf16 (192MB)

    stats_transpose<<<dim3(C_ / 64, NT_ST + 1, B_), 256, 0, stream>>>(
        x, spart, xt, W1, W2, W1b, W2b);
    cb_kernel<<<dim3(B_), 256, 0, stream>>>(W1, b1, spart, cb);
    fused_main<<<dim3(NTS, B_), 512, 0, stream>>>(xt, W1b, W2b, cb, part);
    reduce_kernel<<<dim3(C_ / 256, B_), 256, 0, stream>>>(part, out);
}